// Round 1
// baseline (678.460 us; speedup 1.0000x reference)
//
#include <hip/hip_runtime.h>

// EdgeGate: out[e] = silu(f(e) @ W1 + b1) @ W2 + b2,
//   f(e) = [|H_u - H_v| (128), H_u*H_v (128), S_e, F_e]   (258)
//
// Design (R1):
//  - f16 MFMA 16x16x32 for the [E,256]x[256,128] part (K-dims 256/257 done in
//    fp32 epilogue as rank-2 update). K permuted as interleaved (dim,{diff,prod})
//    so each lane builds its A-fragment from one float4 of H_u and H_v each.
//  - W1[0:256] transposed to f16 in exactly 64 KiB LDS, XOR-swizzled 16B blocks
//    (2-way bank alias only => free). Loaded once per block; NO barrier in main loop.
//  - Block 512 thr = 8 waves x 16 edges = 128-edge tile; 512 blocks grid-stride.

typedef _Float16 half8 __attribute__((ext_vector_type(8)));
typedef float    f32x4 __attribute__((ext_vector_type(4)));

#define TILE_E   128
#define NBLOCKS  512

__device__ __forceinline__ float silu_f(float x) {
    return x / (1.0f + __expf(-x));
}

__global__ __launch_bounds__(512, 4)
void edgegate_kernel(const float* __restrict__ H,
                     const int*   __restrict__ eidx,   // [2, E] int32
                     const float* __restrict__ Se,
                     const float* __restrict__ Fe,
                     const float* __restrict__ W1,     // [258,128]
                     const float* __restrict__ b1,     // [128]
                     const float* __restrict__ W2,     // [128]
                     const float* __restrict__ b2,     // [1]
                     float*       __restrict__ out,    // [E]
                     int E, int ntiles)
{
    // w1t[n][kp]: n = hidden col (0..127), kp = permuted K (0..255), f16.
    // Permutation: kp = c*32 + j, c = chunk (0..7), j in [0,32):
    //   src row = (j&1)*128 + c*16 + (j>>1)   (even j = diff dim, odd j = prod dim)
    // Storage: 16B blocks kb = kp>>3 stored at kb ^ (n&7)  (XOR swizzle).
    __shared__ _Float16 w1t[128 * 256];   // exactly 64 KiB

    const int tid = threadIdx.x;

    // ---- stage W1[0:256][:] -> LDS (transposed, permuted, f16, swizzled)
    {
        const int n = tid & 127;
        const int g = tid >> 7;              // 0..3
        #pragma unroll
        for (int i = 0; i < 8; ++i) {
            const int kb = g + (i << 2);     // 0..31
            half8 tmp;
            #pragma unroll
            for (int j = 0; j < 8; ++j) {
                const int kp  = (kb << 3) + j;
                const int c   = kp >> 5;
                const int jj  = kp & 31;
                const int src = ((jj & 1) << 7) + (c << 4) + (jj >> 1);
                tmp[j] = (_Float16)W1[src * 128 + n];
            }
            const int kbs = kb ^ (n & 7);
            *(half8*)&w1t[n * 256 + (kbs << 3)] = tmp;
        }
    }
    __syncthreads();

    const int lane = tid & 63;
    const int wave = tid >> 6;    // 0..7
    const int q    = lane >> 4;   // quad 0..3
    const int cb   = lane & 15;   // A-row / B-col within 16-tile
    const int swz  = cb & 7;

    for (int tile = blockIdx.x; tile < ntiles; tile += gridDim.x) {
        const int ebase = tile * TILE_E + wave * 16;

        // this lane owns edge m = cb of the wave's 16-edge tile
        int e = ebase + cb;
        if (e >= E) e = E - 1;                 // clamp loads; stores are guarded
        const int u = eidx[e];
        const int v = eidx[E + e];
        const float* up = H + (size_t)u * 128;
        const float* vp = H + (size_t)v * 128;

        f32x4 acc[8];
        #pragma unroll
        for (int t = 0; t < 8; ++t) acc[t] = (f32x4){0.f, 0.f, 0.f, 0.f};

        #pragma unroll
        for (int c = 0; c < 8; ++c) {
            // dims covered by this lane this chunk: c*16 + q*4 .. +3
            const float4 uu = *(const float4*)(up + (c << 4) + (q << 2));
            const float4 vv = *(const float4*)(vp + (c << 4) + (q << 2));
            half8 a;                            // A[m=cb][k=q*8+jj]
            a[0] = (_Float16)fabsf(uu.x - vv.x);
            a[1] = (_Float16)(uu.x * vv.x);
            a[2] = (_Float16)fabsf(uu.y - vv.y);
            a[3] = (_Float16)(uu.y * vv.y);
            a[4] = (_Float16)fabsf(uu.z - vv.z);
            a[5] = (_Float16)(uu.z * vv.z);
            a[6] = (_Float16)fabsf(uu.w - vv.w);
            a[7] = (_Float16)(uu.w * vv.w);

            const int kblk = ((c << 2) + q) ^ swz;   // swizzled 16B block index
            #pragma unroll
            for (int t = 0; t < 8; ++t) {
                const half8 b = *(const half8*)&w1t[((t << 4) + cb) * 256 + (kblk << 3)];
                acc[t] = __builtin_amdgcn_mfma_f32_16x16x32_f16(a, b, acc[t], 0, 0, 0);
            }
        }

        // ---- epilogue: rank-2 tail (S,F rows of W1) + b1, silu, dot with W2
        // C/D layout: col = cb + t*16, row = q*4 + r  ->  edge e0 + r
        const int e0  = ebase + (q << 2);
        const int e0c = (e0 + 3 < E) ? e0 : (E - 4);
        const float4 s4 = *(const float4*)(Se + e0c);
        const float4 f4 = *(const float4*)(Fe + e0c);

        float rs0 = 0.f, rs1 = 0.f, rs2 = 0.f, rs3 = 0.f;
        #pragma unroll
        for (int t = 0; t < 8; ++t) {
            const int col   = (t << 4) + cb;
            const float w256 = W1[32768 + col];   // row 256 (S)
            const float w257 = W1[32896 + col];   // row 257 (F)
            const float b1c  = b1[col];
            const float w2c  = W2[col];
            const f32x4 av = acc[t];
            const float c0 = av[0] + s4.x * w256 + f4.x * w257 + b1c;
            const float c1 = av[1] + s4.y * w256 + f4.y * w257 + b1c;
            const float c2 = av[2] + s4.z * w256 + f4.z * w257 + b1c;
            const float c3 = av[3] + s4.w * w256 + f4.w * w257 + b1c;
            rs0 += silu_f(c0) * w2c;
            rs1 += silu_f(c1) * w2c;
            rs2 += silu_f(c2) * w2c;
            rs3 += silu_f(c3) * w2c;
        }

        // reduce over the 16 lanes of this quad (cols)
        #pragma unroll
        for (int off = 1; off < 16; off <<= 1) {
            rs0 += __shfl_xor(rs0, off);
            rs1 += __shfl_xor(rs1, off);
            rs2 += __shfl_xor(rs2, off);
            rs3 += __shfl_xor(rs3, off);
        }

        if (cb == 0 && e0 < E) {   // E%4==0 -> whole quad-row group in or out
            const float b2v = b2[0];
            out[e0]     = rs0 + b2v;
            out[e0 + 1] = rs1 + b2v;
            out[e0 + 2] = rs2 + b2v;
            out[e0 + 3] = rs3 + b2v;
        }
    }
}

extern "C" void kernel_launch(void* const* d_in, const int* in_sizes, int n_in,
                              void* d_out, int out_size, void* d_ws, size_t ws_size,
                              hipStream_t stream)
{
    const float* H    = (const float*)d_in[0];
    const int*   eidx = (const int*)  d_in[1];   // harness delivers integers as int32
    const float* Se   = (const float*)d_in[2];
    const float* Fe   = (const float*)d_in[3];
    const float* W1   = (const float*)d_in[4];
    const float* b1   = (const float*)d_in[5];
    const float* W2   = (const float*)d_in[6];
    const float* b2   = (const float*)d_in[7];
    float* out = (float*)d_out;

    const int E      = in_sizes[2];                  // 600000
    const int ntiles = (E + TILE_E - 1) / TILE_E;    // 4688
    const int grid   = (NBLOCKS < ntiles) ? NBLOCKS : ntiles;

    hipLaunchKernelGGL(edgegate_kernel, dim3(grid), dim3(512), 0, stream,
                       H, eidx, Se, Fe, W1, b1, W2, b2, out, E, ntiles);
}

// Round 2
// 610.963 us; speedup vs baseline: 1.1105x; 1.1105x over previous
//
#include <hip/hip_runtime.h>

// EdgeGate: out[e] = silu(f(e) @ W1 + b1) @ W2 + b2,
//   f(e) = [|H_u - H_v| (128), H_u*H_v (128), S_e, F_e]   (258)
//
// R2: gather-bytes bound (R1: 612us, FETCH 1.73GB, MfmaUtil 2.6%).
//  - NEW: H converted once per launch to f16 in d_ws (25.6 -> 12.8 MB);
//    gather volume halves (614 -> 307 MB), request count halves.
//  - f16 MFMA 16x16x32; K permuted so each lane builds A-frags for a
//    chunk-PAIR from one half8 (16B) of H_u and H_v each.
//  - W1[0:256] f16-transposed in 64 KiB LDS, XOR-swizzled 16B blocks.
//  - Rows 256/257 (S,F) + b1 + silu + W2-dot in fp32 epilogue.
//  - Block 512 thr = 8 waves x 16 edges; 512 blocks grid-stride.

typedef _Float16      half8  __attribute__((ext_vector_type(8)));
typedef _Float16      half4v __attribute__((ext_vector_type(4)));
typedef unsigned short ushort8 __attribute__((ext_vector_type(8)));
typedef float         f32x4  __attribute__((ext_vector_type(4)));

#define TILE_E   128
#define NBLOCKS  512

__device__ __forceinline__ float silu_f(float x) {
    return x / (1.0f + __expf(-x));
}

__global__ __launch_bounds__(256)
void cvt_h_kernel(const float* __restrict__ H, _Float16* __restrict__ Hh, int n4) {
    int i = blockIdx.x * blockDim.x + threadIdx.x;
    if (i < n4) {
        const float4 f = ((const float4*)H)[i];
        half4v h;
        h[0] = (_Float16)f.x; h[1] = (_Float16)f.y;
        h[2] = (_Float16)f.z; h[3] = (_Float16)f.w;
        ((half4v*)Hh)[i] = h;
    }
}

// K-permutation (kp in [0,256)): kp = c*32 + q*8 + j  (c = mfma chunk, q = quad,
// j = lane element). Source dim d = (c>>1)*32 + q*8 + (c&1)*4 + (j>>1);
// j even -> |H_u-H_v| row d, j odd -> H_u*H_v row 128+d.
// So per chunk-PAIR (c8=c>>1) a lane needs dims c8*32+q*8 .. +7: ONE half8 load.

template<bool F16>
__global__ __launch_bounds__(512, 4)
void edgegate_kernel(const float* __restrict__ H,
                     const _Float16* __restrict__ Hh,
                     const int*   __restrict__ eidx,   // [2, E] int32
                     const float* __restrict__ Se,
                     const float* __restrict__ Fe,
                     const float* __restrict__ W1,     // [258,128]
                     const float* __restrict__ b1,
                     const float* __restrict__ W2,
                     const float* __restrict__ b2,
                     float*       __restrict__ out,
                     int E, int ntiles)
{
    __shared__ _Float16 w1t[128 * 256];   // 64 KiB, [n][kp] swizzled 16B blocks

    const int tid = threadIdx.x;
    {
        const int n = tid & 127;
        const int g = tid >> 7;
        #pragma unroll
        for (int i = 0; i < 8; ++i) {
            const int kb = g + (i << 2);
            half8 tmp;
            #pragma unroll
            for (int j = 0; j < 8; ++j) {
                const int kp = (kb << 3) + j;
                const int c  = kp >> 5;
                const int r5 = kp & 31;
                const int qq = r5 >> 3;
                const int jj = r5 & 7;
                const int d  = ((c >> 1) << 5) + (qq << 3) + ((c & 1) << 2) + (jj >> 1);
                const int src = ((jj & 1) << 7) + d;
                tmp[j] = (_Float16)W1[src * 128 + n];
            }
            *(half8*)&w1t[n * 256 + ((kb ^ (n & 7)) << 3)] = tmp;
        }
    }
    __syncthreads();

    const int lane = tid & 63;
    const int wave = tid >> 6;
    const int q    = lane >> 4;
    const int cb   = lane & 15;
    const int swz  = cb & 7;

    for (int tile = blockIdx.x; tile < ntiles; tile += gridDim.x) {
        const int ebase = tile * TILE_E + wave * 16;

        int e = ebase + cb;
        if (e >= E) e = E - 1;
        const int u = eidx[e];
        const int v = eidx[E + e];

        f32x4 acc[8];
        #pragma unroll
        for (int t = 0; t < 8; ++t) acc[t] = (f32x4){0.f, 0.f, 0.f, 0.f};

        if constexpr (F16) {
            const _Float16* up = Hh + (size_t)u * 128;
            const _Float16* vp = Hh + (size_t)v * 128;
            #pragma unroll
            for (int c8 = 0; c8 < 4; ++c8) {
                const half8 u8 = *(const half8*)(up + (c8 << 5) + (q << 3));
                const half8 v8 = *(const half8*)(vp + (c8 << 5) + (q << 3));
                half8 d8 = u8 - v8;
                ushort8 du = *(ushort8*)&d8;
                du = du & (unsigned short)0x7FFF;        // |diff|
                const half8 da = *(half8*)&du;
                const half8 p8 = u8 * v8;

                half8 ae, ao;
                ae[0]=da[0]; ae[1]=p8[0]; ae[2]=da[1]; ae[3]=p8[1];
                ae[4]=da[2]; ae[5]=p8[2]; ae[6]=da[3]; ae[7]=p8[3];
                ao[0]=da[4]; ao[1]=p8[4]; ao[2]=da[5]; ao[3]=p8[5];
                ao[4]=da[6]; ao[5]=p8[6]; ao[6]=da[7]; ao[7]=p8[7];

                const int kb0 = (((c8 << 1) + 0) * 4 + q) ^ swz;
                const int kb1 = (((c8 << 1) + 1) * 4 + q) ^ swz;
                #pragma unroll
                for (int t = 0; t < 8; ++t) {
                    const half8 b0 = *(const half8*)&w1t[((t << 4) + cb) * 256 + (kb0 << 3)];
                    acc[t] = __builtin_amdgcn_mfma_f32_16x16x32_f16(ae, b0, acc[t], 0, 0, 0);
                }
                #pragma unroll
                for (int t = 0; t < 8; ++t) {
                    const half8 b1f = *(const half8*)&w1t[((t << 4) + cb) * 256 + (kb1 << 3)];
                    acc[t] = __builtin_amdgcn_mfma_f32_16x16x32_f16(ao, b1f, acc[t], 0, 0, 0);
                }
            }
        } else {
            const float* up = H + (size_t)u * 128;
            const float* vp = H + (size_t)v * 128;
            #pragma unroll
            for (int c8 = 0; c8 < 4; ++c8) {
                const float4 uu0 = *(const float4*)(up + (c8 << 5) + (q << 3));
                const float4 vv0 = *(const float4*)(vp + (c8 << 5) + (q << 3));
                const float4 uu1 = *(const float4*)(up + (c8 << 5) + (q << 3) + 4);
                const float4 vv1 = *(const float4*)(vp + (c8 << 5) + (q << 3) + 4);
                half8 ae, ao;
                ae[0]=(_Float16)fabsf(uu0.x-vv0.x); ae[1]=(_Float16)(uu0.x*vv0.x);
                ae[2]=(_Float16)fabsf(uu0.y-vv0.y); ae[3]=(_Float16)(uu0.y*vv0.y);
                ae[4]=(_Float16)fabsf(uu0.z-vv0.z); ae[5]=(_Float16)(uu0.z*vv0.z);
                ae[6]=(_Float16)fabsf(uu0.w-vv0.w); ae[7]=(_Float16)(uu0.w*vv0.w);
                ao[0]=(_Float16)fabsf(uu1.x-vv1.x); ao[1]=(_Float16)(uu1.x*vv1.x);
                ao[2]=(_Float16)fabsf(uu1.y-vv1.y); ao[3]=(_Float16)(uu1.y*vv1.y);
                ao[4]=(_Float16)fabsf(uu1.z-vv1.z); ao[5]=(_Float16)(uu1.z*vv1.z);
                ao[6]=(_Float16)fabsf(uu1.w-vv1.w); ao[7]=(_Float16)(uu1.w*vv1.w);
                const int kb0 = (((c8 << 1) + 0) * 4 + q) ^ swz;
                const int kb1 = (((c8 << 1) + 1) * 4 + q) ^ swz;
                #pragma unroll
                for (int t = 0; t < 8; ++t) {
                    const half8 b0 = *(const half8*)&w1t[((t << 4) + cb) * 256 + (kb0 << 3)];
                    acc[t] = __builtin_amdgcn_mfma_f32_16x16x32_f16(ae, b0, acc[t], 0, 0, 0);
                }
                #pragma unroll
                for (int t = 0; t < 8; ++t) {
                    const half8 b1f = *(const half8*)&w1t[((t << 4) + cb) * 256 + (kb1 << 3)];
                    acc[t] = __builtin_amdgcn_mfma_f32_16x16x32_f16(ao, b1f, acc[t], 0, 0, 0);
                }
            }
        }

        // ---- epilogue: rank-2 tail (rows 256/257) + b1, silu, dot W2
        const int e0  = ebase + (q << 2);
        const int e0c = (e0 + 3 < E) ? e0 : (E - 4);
        const float4 s4 = *(const float4*)(Se + e0c);
        const float4 f4 = *(const float4*)(Fe + e0c);

        float rs0 = 0.f, rs1 = 0.f, rs2 = 0.f, rs3 = 0.f;
        #pragma unroll
        for (int t = 0; t < 8; ++t) {
            const int col    = (t << 4) + cb;
            const float w256 = W1[32768 + col];
            const float w257 = W1[32896 + col];
            const float b1c  = b1[col];
            const float w2c  = W2[col];
            const f32x4 av = acc[t];
            rs0 += silu_f(av[0] + s4.x * w256 + f4.x * w257 + b1c) * w2c;
            rs1 += silu_f(av[1] + s4.y * w256 + f4.y * w257 + b1c) * w2c;
            rs2 += silu_f(av[2] + s4.z * w256 + f4.z * w257 + b1c) * w2c;
            rs3 += silu_f(av[3] + s4.w * w256 + f4.w * w257 + b1c) * w2c;
        }

        #pragma unroll
        for (int off = 1; off < 16; off <<= 1) {
            rs0 += __shfl_xor(rs0, off);
            rs1 += __shfl_xor(rs1, off);
            rs2 += __shfl_xor(rs2, off);
            rs3 += __shfl_xor(rs3, off);
        }

        if (cb == 0 && e0 < E) {
            const float b2v = b2[0];
            out[e0]     = rs0 + b2v;
            out[e0 + 1] = rs1 + b2v;
            out[e0 + 2] = rs2 + b2v;
            out[e0 + 3] = rs3 + b2v;
        }
    }
}

extern "C" void kernel_launch(void* const* d_in, const int* in_sizes, int n_in,
                              void* d_out, int out_size, void* d_ws, size_t ws_size,
                              hipStream_t stream)
{
    const float* H    = (const float*)d_in[0];
    const int*   eidx = (const int*)  d_in[1];
    const float* Se   = (const float*)d_in[2];
    const float* Fe   = (const float*)d_in[3];
    const float* W1   = (const float*)d_in[4];
    const float* b1   = (const float*)d_in[5];
    const float* W2   = (const float*)d_in[6];
    const float* b2   = (const float*)d_in[7];
    float* out = (float*)d_out;

    const int nH     = in_sizes[0];                  // 6.4M
    const int E      = in_sizes[2];                  // 600000
    const int ntiles = (E + TILE_E - 1) / TILE_E;
    const int grid   = (NBLOCKS < ntiles) ? NBLOCKS : ntiles;

    const bool f16ok = ws_size >= (size_t)nH * sizeof(_Float16);

    if (f16ok) {
        _Float16* Hh = (_Float16*)d_ws;
        const int n4 = nH / 4;
        hipLaunchKernelGGL(cvt_h_kernel, dim3((n4 + 255) / 256), dim3(256), 0, stream,
                           H, Hh, n4);
        hipLaunchKernelGGL((edgegate_kernel<true>), dim3(grid), dim3(512), 0, stream,
                           H, Hh, eidx, Se, Fe, W1, b1, W2, b2, out, E, ntiles);
    } else {
        hipLaunchKernelGGL((edgegate_kernel<false>), dim3(grid), dim3(512), 0, stream,
                           H, (const _Float16*)nullptr, eidx, Se, Fe, W1, b1, W2, b2,
                           out, E, ntiles);
    }
}